// Round 8
// baseline (519.170 us; speedup 1.0000x reference)
//
#include <hip/hip_runtime.h>
#include <hip/hip_cooperative_groups.h>

namespace cg = cooperative_groups;

#define DIM   4096
#define KVDIM 1024   // n_kv_heads * head_dim
#define NB    8      // batch
#define TOTAL 16384
#define NBLK  1024   // 4 blocks/CU on 256 CUs -> co-resident (verified launches in R4)
#define BCAST_BLOCKS 4096

// ---------------- fused cooperative kernel (R4 structure, plain stores) -------
// R4 counters: this exact loop structure compiles to VGPR=32 and launches
// cooperatively. Only delta vs R4: phase-3 NT stores -> plain float4 stores
// (NT measured 1.1 TB/s; plain dwordx4 measured 6.4 TB/s on the harness fill).
__global__ __launch_bounds__(256, 4)
void fused_pca(const float* __restrict__ emb, const float* __restrict__ wup,
               const float* __restrict__ wdn, const int* __restrict__ seqlen,
               float* __restrict__ x, float* __restrict__ y,
               float* __restrict__ out) {
    cg::grid_group grid = cg::this_grid();
    const int lane = threadIdx.x & 63;
    const int wid  = blockIdx.x * 4 + (threadIdx.x >> 6);   // 0..4095

    // ---- phase 1: up-projection, 2 dots per wave ----
    #pragma unroll
    for (int i = 0; i < 2; i++) {
        int d = wid * 2 + i;           // 0..8191
        int j = d >> 3;                // 0..1023
        int b = d & 7;
        const float4* e = (const float4*)(emb + b * DIM);
        const float4* w = (const float4*)(wup + (long)j * DIM);
        float acc = 0.f;
        for (int it = lane; it < DIM / 4; it += 64) {
            float4 ev = e[it], wv = w[it];
            acc += ev.x * wv.x + ev.y * wv.y + ev.z * wv.z + ev.w * wv.w;
        }
        #pragma unroll
        for (int off = 32; off; off >>= 1) acc += __shfl_down(acc, off, 64);
        if (lane == 0) x[b * KVDIM + j] = acc;
    }

    grid.sync();

    // ---- phase 2: down-projection, one o per wave, all 8 batches ----
    {
        int o = wid;                   // 0..4095
        const float4* w = (const float4*)(wdn + (long)o * DIM);
        float acc[NB];
        #pragma unroll
        for (int b = 0; b < NB; b++) acc[b] = 0.f;
        for (int it = lane; it < DIM / 4; it += 64) {
            int k0 = it * 4;
            int kv = ((k0 >> 9) << 7) + (k0 & 127);   // 16B-aligned gather
            float4 wv = w[it];
            #pragma unroll
            for (int b = 0; b < NB; b++) {
                const float4 xv = *(const float4*)(x + b * KVDIM + kv);
                acc[b] += xv.x * wv.x + xv.y * wv.y + xv.z * wv.z + xv.w * wv.w;
            }
        }
        #pragma unroll
        for (int b = 0; b < NB; b++) {
            #pragma unroll
            for (int off = 32; off; off >>= 1) acc[b] += __shfl_down(acc[b], off, 64);
            if (lane == 0) y[b * DIM + o] = acc[b];
        }
    }

    grid.sync();

    // ---- phase 3: ragged broadcast, 16 rows per block, plain float4 stores ----
    int c0 = seqlen[0];
    int c1 = c0 + seqlen[1];
    int c2 = c1 + seqlen[2];
    int c3 = c2 + seqlen[3];
    int c4 = c3 + seqlen[4];
    int c5 = c4 + seqlen[5];
    int c6 = c5 + seqlen[6];
    for (int g = 0; g < TOTAL / NBLK; g++) {
        int row = blockIdx.x + g * NBLK;
        int s = (row >= c0) + (row >= c1) + (row >= c2) + (row >= c3)
              + (row >= c4) + (row >= c5) + (row >= c6);
        const float4* yr = (const float4*)(y + s * DIM);
        float4* orow = (float4*)(out + (long)row * DIM);
        for (int c = threadIdx.x; c < DIM / 4; c += 256)
            orow[c] = yr[c];
    }
}

// ---------------- fallback pipeline (R6, 348 us, verified) --------------------
__global__ __launch_bounds__(256)
void k_up(const float* __restrict__ emb, const float* __restrict__ wup,
          float* __restrict__ x) {
    int wid  = blockIdx.x * 4 + (threadIdx.x >> 6);
    int lane = threadIdx.x & 63;
    int j = wid >> 3;
    int b = wid & 7;
    const float4* e = (const float4*)(emb + b * DIM);
    const float4* w = (const float4*)(wup + (long)j * DIM);
    float acc = 0.f;
    #pragma unroll
    for (int ii = 0; ii < DIM / 4 / 64; ii++) {
        int it = ii * 64 + lane;
        float4 ev = e[it], wv = w[it];
        acc += ev.x * wv.x + ev.y * wv.y + ev.z * wv.z + ev.w * wv.w;
    }
    #pragma unroll
    for (int off = 32; off; off >>= 1) acc += __shfl_down(acc, off, 64);
    if (lane == 0) x[b * KVDIM + j] = acc;
}

__global__ __launch_bounds__(256)
void k_down(const float* __restrict__ x, const float* __restrict__ wdn,
            float* __restrict__ y) {
    __shared__ float part[4][NB];
    int o    = blockIdx.x;
    int wv   = threadIdx.x >> 6;
    int lane = threadIdx.x & 63;
    const float4* w = (const float4*)(wdn + (long)o * DIM);
    float acc[NB];
    #pragma unroll
    for (int b = 0; b < NB; b++) acc[b] = 0.f;
    #pragma unroll
    for (int ii = 0; ii < 4; ii++) {
        int it = wv * 256 + ii * 64 + lane;
        int k0 = it * 4;
        int kv = ((k0 >> 9) << 7) + (k0 & 127);
        float4 wvv = w[it];
        #pragma unroll
        for (int b = 0; b < NB; b++) {
            const float4 xv = *(const float4*)(x + b * KVDIM + kv);
            acc[b] += xv.x * wvv.x + xv.y * wvv.y + xv.z * wvv.z + xv.w * wvv.w;
        }
    }
    #pragma unroll
    for (int b = 0; b < NB; b++) {
        #pragma unroll
        for (int off = 32; off; off >>= 1) acc[b] += __shfl_down(acc[b], off, 64);
    }
    if (lane == 0) {
        #pragma unroll
        for (int b = 0; b < NB; b++) part[wv][b] = acc[b];
    }
    __syncthreads();
    if (threadIdx.x < NB) {
        int b = threadIdx.x;
        y[b * DIM + o] = part[0][b] + part[1][b] + part[2][b] + part[3][b];
    }
}

__global__ __launch_bounds__(256)
void k_bcast(const float* __restrict__ y, const int* __restrict__ seqlen,
             float4* __restrict__ out) {
    int c0 = seqlen[0];
    int c1 = c0 + seqlen[1];
    int c2 = c1 + seqlen[2];
    int c3 = c2 + seqlen[3];
    int c4 = c3 + seqlen[4];
    int c5 = c4 + seqlen[5];
    int c6 = c5 + seqlen[6];
    #pragma unroll
    for (int g = 0; g < TOTAL / BCAST_BLOCKS; g++) {
        int row = blockIdx.x + g * BCAST_BLOCKS;
        int s = (row >= c0) + (row >= c1) + (row >= c2) + (row >= c3)
              + (row >= c4) + (row >= c5) + (row >= c6);
        const float4* yr = (const float4*)(y + s * DIM);
        float4* orow = out + (long)row * (DIM / 4);
        #pragma unroll
        for (int c = threadIdx.x; c < DIM / 4; c += 256)
            orow[c] = yr[c];
    }
}

extern "C" void kernel_launch(void* const* d_in, const int* in_sizes, int n_in,
                              void* d_out, int out_size, void* d_ws, size_t ws_size,
                              hipStream_t stream) {
    const float* emb = (const float*)d_in[0];
    const float* wup = (const float*)d_in[1];
    const float* wdn = (const float*)d_in[2];
    const int* seqlen = (const int*)d_in[3];

    float* x = (float*)d_ws;           // 8*1024 fp32 = 32 KB
    float* y = x + NB * KVDIM;         // 8*4096 fp32 = 128 KB
    float* out = (float*)d_out;

    void* args[] = {(void*)&emb, (void*)&wup, (void*)&wdn, (void*)&seqlen,
                    (void*)&x, (void*)&y, (void*)&out};
    hipError_t err = hipLaunchCooperativeKernel((const void*)fused_pca,
                                                dim3(NBLK), dim3(256),
                                                args, 0, stream);
    if (err != hipSuccess) {
        // deterministic fallback: proven 3-kernel pipeline
        k_up   <<<NB * KVDIM / 4, 256, 0, stream>>>(emb, wup, x);
        k_down <<<DIM,            256, 0, stream>>>(x, wdn, y);
        k_bcast<<<BCAST_BLOCKS,   256, 0, stream>>>(y, seqlen, (float4*)out);
    }
}